// Round 4
// baseline (915.857 us; speedup 1.0000x reference)
//
#include <hip/hip_runtime.h>

#define TT 2048
#define BB 4
#define DD 1024
#define HH 16
#define HDIM 64
#define MM (TT*BB)   // 8192 rows, row index m = t*BB + b

typedef __attribute__((ext_vector_type(4))) float float4v;
typedef _Float16 half8 __attribute__((ext_vector_type(8)));
typedef _Float16 half4 __attribute__((ext_vector_type(4)));
typedef _Float16 half2v __attribute__((ext_vector_type(2)));

static __device__ __forceinline__ half4 pk4(float a, float b, float c, float d) {
    half2v h0 = __builtin_bit_cast(half2v, __builtin_amdgcn_cvt_pkrtz(a, b));
    half2v h1 = __builtin_bit_cast(half2v, __builtin_amdgcn_cvt_pkrtz(c, d));
    half4 hv; hv[0]=h0[0]; hv[1]=h0[1]; hv[2]=h1[0]; hv[3]=h1[1];
    return hv;
}

// ---------------------------------------------------------------------------
// Kernel 1: QKV projection, fp16 GEMM.
//   z==0 (Q): out = (x@Wq.T + bq) * (0.125*log2e), layout (B,H,T,HD)
//   z==1 (K): out = x@Wk.T + bk, layout (B,H,T,HD)
//   z==2 (V): out = x@Wv.T + bv, layout (B,H,HD,T)  <-- pre-transposed
// Tile 128x128, BK=64, 4 waves (2x2).
// ---------------------------------------------------------------------------
#define K1_LD 72   // 64 + 8 halfs pad: rows 16B-aligned (144B), 2-way banks (free)

__global__ __launch_bounds__(256) void qkv_proj(
    const float* __restrict__ xq, const float* __restrict__ xk, const float* __restrict__ xv,
    const float* __restrict__ wq, const float* __restrict__ wk, const float* __restrict__ wv,
    const float* __restrict__ bq, const float* __restrict__ bk, const float* __restrict__ bv,
    _Float16* __restrict__ dq, _Float16* __restrict__ dk, _Float16* __restrict__ dv)
{
    const int z = blockIdx.z;
    const float* X  = (z==0)?xq:((z==1)?xk:xv);
    const float* W  = (z==0)?wq:((z==1)?wk:wv);
    const float* Bb = (z==0)?bq:((z==1)?bk:bv);
    _Float16* Dst   = (z==0)?dq:((z==1)?dk:dv);
    const float post = (z==0) ? 0.125f*1.44269504088896341f : 1.0f;

    __shared__ __attribute__((aligned(16))) _Float16 As[128*K1_LD];
    __shared__ __attribute__((aligned(16))) _Float16 Bs[128*K1_LD];

    const int tid  = threadIdx.x;
    const int lane = tid & 63;
    const int wid  = tid >> 6;
    const int wm   = wid >> 1, wn = wid & 1;
    const int m0   = blockIdx.y * 128;
    const int n0   = blockIdx.x * 128;
    const int lrow = lane & 15;
    const int lk   = (lane >> 4) * 8;

    float4v acc[4][4];
    for (int i=0;i<4;i++) for (int j=0;j<4;j++) acc[i][j] = (float4v){0.f,0.f,0.f,0.f};

    for (int k0 = 0; k0 < DD; k0 += 64) {
        __syncthreads();
        #pragma unroll
        for (int s = 0; s < 8; s++) {
            int idx = tid + s*256;
            int row = idx >> 4;          // 16 float4 per 64-float row
            int c   = (idx & 15) * 4;
            float4v va = *(const float4v*)(X + (size_t)(m0+row)*DD + k0 + c);
            *(half4*)&As[row*K1_LD + c] = pk4(va[0], va[1], va[2], va[3]);
        }
        #pragma unroll
        for (int s = 0; s < 8; s++) {
            int idx = tid + s*256;
            int row = idx >> 4;
            int c   = (idx & 15) * 4;
            float4v vb = *(const float4v*)(W + (size_t)(n0+row)*DD + k0 + c);
            *(half4*)&Bs[row*K1_LD + c] = pk4(vb[0], vb[1], vb[2], vb[3]);
        }
        __syncthreads();
        #pragma unroll
        for (int kc=0; kc<2; kc++) {
            int kof = kc*32 + lk;
            half8 a[4], b[4];
            for (int i=0;i<4;i++) {
                a[i] = *(const half8*)&As[(wm*64 + i*16 + lrow)*K1_LD + kof];
                b[i] = *(const half8*)&Bs[(wn*64 + i*16 + lrow)*K1_LD + kof];
            }
            for (int i=0;i<4;i++)
            for (int j=0;j<4;j++)
                acc[i][j] = __builtin_amdgcn_mfma_f32_16x16x32_f16(a[i], b[j], acc[i][j],0,0,0);
        }
    }
    // epilogue: + bias, optional scale, -> fp16, scatter
    for (int j=0;j<4;j++) {
        int n = n0 + wn*64 + j*16 + lrow;
        float bias = Bb[n];
        int h = n >> 6, hd = n & 63;
        for (int i=0;i<4;i++)
        for (int r=0;r<4;r++) {
            int m = m0 + wm*64 + i*16 + (lane>>4)*4 + r;
            int t = m >> 2, b = m & 3;
            _Float16 val = (_Float16)((acc[i][j][r] + bias) * post);
            if (z == 2)
                Dst[((size_t)(b*HH + h)*HDIM + hd)*TT + t] = val;   // V^T: (B,H,HD,T)
            else
                Dst[((size_t)(b*HH + h)*TT + t)*HDIM + hd] = val;   // (B,H,T,HD)
        }
    }
}

// ---------------------------------------------------------------------------
// Kernel 2: flash-style attention, fp16, max-free softmax, BARRIER-FREE loop:
//  - K fragments loaded directly from global (B,H,T,HD): 16B contiguous
//  - V fragments loaded directly from global V^T (B,H,HD,T): 16B contiguous
//  - P round-trips through a wave-private LDS region (same-wave DS ordering)
// q-tile 128 (32 q/wave), key-tile 64. Q pre-scaled by 0.125*log2e, so
// P = exp2(S) directly. LDS 18.4 KB -> 8 blocks/CU.
// ---------------------------------------------------------------------------
#define AT_LD 72   // stride: 144B rows, 16B aligned, 2-way bank alias (free)

__global__ __launch_bounds__(256, 8) void attn(
    const _Float16* __restrict__ Qg, const _Float16* __restrict__ Kg,
    const _Float16* __restrict__ Vtg, _Float16* __restrict__ Ctx)
{
    __shared__ __attribute__((aligned(16))) _Float16 Pl[128*AT_LD];   // [q_local][t_local]

    const int qt  = blockIdx.x;   // 0..15
    const int bh  = blockIdx.y;   // 0..63
    const int tid = threadIdx.x, lane = tid & 63, w = tid >> 6;
    const int lrow = lane & 15, lg = lane >> 4;

    const _Float16* Qb  = Qg  + ((size_t)bh*TT + qt*128)*HDIM;
    const _Float16* Kb  = Kg  + (size_t)bh*TT*HDIM;
    const _Float16* Vtb = Vtg + (size_t)bh*HDIM*TT;   // [hd][t]

    // preload Q A-frags: wave w owns q rows [w*32, w*32+32)
    half8 qf[2][2];
    for (int i=0;i<2;i++) for (int kc=0;kc<2;kc++)
        qf[i][kc] = *(const half8*)(Qb + (size_t)(w*32 + i*16 + lrow)*HDIM + kc*32 + lg*8);

    float4v oacc[2][4];
    for (int i=0;i<2;i++) for (int j=0;j<4;j++) oacc[i][j] = (float4v){0.f,0.f,0.f,0.f};
    float lsum[2][4];
    for (int i=0;i<2;i++) for (int r=0;r<4;r++) lsum[i][r] = 0.f;

    for (int kt = 0; kt < 32; kt++) {
        const int t0 = kt*64;
        const _Float16* Ksrc = Kb + (size_t)t0*HDIM;

        // S = Q K^T  (Q pre-scaled)
        float4v sacc[2][4];
        for (int i=0;i<2;i++) for (int j=0;j<4;j++) sacc[i][j] = (float4v){0.f,0.f,0.f,0.f};
        #pragma unroll
        for (int kc=0;kc<2;kc++) {
            half8 kf[4];
            for (int j=0;j<4;j++)
                kf[j] = *(const half8*)(Ksrc + (size_t)(j*16 + lrow)*HDIM + kc*32 + lg*8);
            for (int i=0;i<2;i++)
            for (int j=0;j<4;j++)
                sacc[i][j] = __builtin_amdgcn_mfma_f32_16x16x32_f16(qf[i][kc], kf[j], sacc[i][j],0,0,0);
        }

        // P = exp2(S); partial row-sums; P -> wave-private LDS rows
        #pragma unroll
        for (int i=0;i<2;i++)
        #pragma unroll
        for (int j=0;j<4;j++)
        #pragma unroll
        for (int r=0;r<4;r++) {
            float p = exp2f(sacc[i][j][r]);
            lsum[i][r] += p;
            Pl[(w*32 + i*16 + lg*4 + r)*AT_LD + j*16 + lrow] = (_Float16)p;
        }

        // O += P @ V   (V frags straight from global V^T)
        #pragma unroll
        for (int kc=0;kc<2;kc++) {
            int kof = kc*32 + lg*8;
            half8 af[2], bf[4];
            for (int i=0;i<2;i++)
                af[i] = *(const half8*)&Pl[(w*32 + i*16 + lrow)*AT_LD + kof];
            for (int jo=0;jo<4;jo++)
                bf[jo] = *(const half8*)(Vtb + (size_t)(jo*16 + lrow)*TT + t0 + kof);
            for (int i=0;i<2;i++)
            for (int jo=0;jo<4;jo++)
                oacc[i][jo] = __builtin_amdgcn_mfma_f32_16x16x32_f16(af[i], bf[jo], oacc[i][jo],0,0,0);
        }
    }

    // final row-sum reduce across the 16 lanes sharing lg
    for (int i=0;i<2;i++)
    for (int r=0;r<4;r++) {
        float s = lsum[i][r];
        for (int off=1; off<16; off<<=1) s += __shfl_xor(s, off, 64);
        lsum[i][r] = s;
    }

    // finalize: O /= l, write ctx fp16 in (T,B,D)
    const int b = bh >> 4, h = bh & 15;
    for (int i=0;i<2;i++)
    for (int r=0;r<4;r++) {
        float inv = 1.f / lsum[i][r];
        int t = qt*128 + w*32 + i*16 + lg*4 + r;
        for (int jo=0;jo<4;jo++) {
            int hd = jo*16 + lrow;
            Ctx[(size_t)(t*BB + b)*DD + h*HDIM + hd] = (_Float16)(oacc[i][jo][r] * inv);
        }
    }
}

// ---------------------------------------------------------------------------
// Kernel 3: out = (ctx @ Wo.T + bo) * time_decay, fp16 GEMM, fp32 out.
// ---------------------------------------------------------------------------
__global__ __launch_bounds__(256) void out_proj(
    const _Float16* __restrict__ Cx, const float* __restrict__ Wo,
    const float* __restrict__ bo, const float* __restrict__ td,
    float* __restrict__ Out)
{
    __shared__ __attribute__((aligned(16))) _Float16 At[128*K1_LD];
    __shared__ __attribute__((aligned(16))) _Float16 Bt[128*K1_LD];

    const int tid  = threadIdx.x, lane = tid & 63, wid = tid >> 6;
    const int wm   = wid >> 1, wn = wid & 1;
    const int m0   = blockIdx.y*128, n0 = blockIdx.x*128;
    const int lrow = lane & 15, lk = (lane>>4)*8;

    float4v acc[4][4];
    for (int i=0;i<4;i++) for (int j=0;j<4;j++) acc[i][j]=(float4v){0.f,0.f,0.f,0.f};

    for (int k0=0; k0<DD; k0+=64) {
        __syncthreads();
        // stage ctx tile (already fp16): 128x64 halfs, 4 x half8 per thread
        #pragma unroll
        for (int s=0;s<4;s++) {
            int idx = tid + s*256;
            int row = idx >> 3;          // 8 half8 per 64-half row
            int c   = (idx & 7)*8;
            *(half8*)&At[row*K1_LD + c] = *(const half8*)(Cx + (size_t)(m0+row)*DD + k0 + c);
        }
        // stage Wo tile fp32 -> fp16
        #pragma unroll
        for (int s=0;s<8;s++) {
            int idx = tid + s*256;
            int row = idx >> 4;
            int c   = (idx & 15)*4;
            float4v vb = *(const float4v*)(Wo + (size_t)(n0+row)*DD + k0 + c);
            *(half4*)&Bt[row*K1_LD + c] = pk4(vb[0], vb[1], vb[2], vb[3]);
        }
        __syncthreads();
        #pragma unroll
        for (int kc=0;kc<2;kc++) {
            int kof = kc*32 + lk;
            half8 a[4], b[4];
            for (int i=0;i<4;i++) {
                a[i] = *(const half8*)&At[(wm*64 + i*16 + lrow)*K1_LD + kof];
                b[i] = *(const half8*)&Bt[(wn*64 + i*16 + lrow)*K1_LD + kof];
            }
            for (int i=0;i<4;i++)
            for (int j=0;j<4;j++)
                acc[i][j] = __builtin_amdgcn_mfma_f32_16x16x32_f16(a[i], b[j], acc[i][j],0,0,0);
        }
    }
    for (int j=0;j<4;j++) {
        int n = n0 + wn*64 + j*16 + lrow;
        float bias = bo[n];
        for (int i=0;i<4;i++)
        for (int r=0;r<4;r++) {
            int m = m0 + wm*64 + i*16 + (lane>>4)*4 + r;
            size_t off = (size_t)m*DD + n;
            Out[off] = (acc[i][j][r] + bias) * td[off];
        }
    }
}

// ---------------------------------------------------------------------------
extern "C" void kernel_launch(void* const* d_in, const int* in_sizes, int n_in,
                              void* d_out, int out_size, void* d_ws, size_t ws_size,
                              hipStream_t stream) {
    const float* q  = (const float*)d_in[0];
    const float* k  = (const float*)d_in[1];
    const float* v  = (const float*)d_in[2];
    const float* td = (const float*)d_in[3];
    const float* Wq = (const float*)d_in[4];
    const float* bq = (const float*)d_in[5];
    const float* Wk = (const float*)d_in[6];
    const float* bk = (const float*)d_in[7];
    const float* Wv = (const float*)d_in[8];
    const float* bv = (const float*)d_in[9];
    const float* Wo = (const float*)d_in[10];
    const float* bo = (const float*)d_in[11];
    float* out = (float*)d_out;

    // workspace: Q (B,H,T,HD) + K (B,H,T,HD) + V^T (B,H,HD,T) + ctx (T,B,D), fp16 = 64 MB
    _Float16* Qb = (_Float16*)d_ws;
    _Float16* Kb = Qb + (size_t)MM*DD;
    _Float16* Vt = Kb + (size_t)MM*DD;
    _Float16* Cx = Vt + (size_t)MM*DD;

    qkv_proj<<<dim3(8, 64, 3), 256, 0, stream>>>(q,k,v, Wq,Wk,Wv, bq,bk,bv, Qb,Kb,Vt);
    attn    <<<dim3(16, 64),   256, 0, stream>>>(Qb, Kb, Vt, Cx);
    out_proj<<<dim3(8, 64),    256, 0, stream>>>(Cx, Wo, bo, td, out);
}